// Round 1
// baseline (475.438 us; speedup 1.0000x reference)
//
#include <hip/hip_runtime.h>

typedef __attribute__((ext_vector_type(8))) short short8;
typedef __attribute__((ext_vector_type(4))) float floatx4;
typedef unsigned short ushort_t;
typedef unsigned int uint32;

// ---------- helpers ----------

__device__ __forceinline__ uint32 f2bf_bits(float f) {
  uint32 u = __builtin_bit_cast(uint32, f);
  u += 0x7fffu + ((u >> 16) & 1u);   // round-to-nearest-even
  return u >> 16;
}

__device__ __forceinline__ float tanh_fast(float x) {
  // tanh(x) = 1 - 2/(e^{2x}+1); robust at +-inf of expf
  float e = __expf(2.0f * x);
  return 1.0f - 2.0f * __builtin_amdgcn_rcpf(e + 1.0f);
}

__device__ __forceinline__ void gl_lds16(const void* g, void* l) {
  // async global->LDS, 16B per lane; LDS dest = wave-uniform base + lane*16
  __builtin_amdgcn_global_load_lds((const __attribute__((address_space(1))) void*)g,
                                   (__attribute__((address_space(3))) void*)l,
                                   16, 0, 0);
}

// ---------- prep: fold weights, cast to bf16, pre-transpose to [n][k] ----------
// ws layout:
//   Wtm      [16][128 o][256 i] bf16   @ 0        (W_mid * w_inp, transposed)
//   Wtr      [256 o][2048 k]    bf16   @ 1 MB     (W_root transposed)
//   bias_eff [16][128]          f32    @ 2 MB     (b_mid + sum_i pbias*W_mid)
//   midbuf   [16384][2048]      bf16   @ 4 MB     (tanh outputs)

__global__ __launch_bounds__(256) void prep(const float* __restrict__ w_inp,
                                            const float* __restrict__ pbias,
                                            const float* __restrict__ W_mid,
                                            const float* __restrict__ b_mid,
                                            const float* __restrict__ W_root,
                                            ushort_t* __restrict__ Wtm,
                                            ushort_t* __restrict__ Wtr,
                                            float* __restrict__ bias_eff) {
  const int b = blockIdx.x, t = threadIdx.x;
  if (b < 2048) {
    // W'_mid: read coalesced over o, write transposed
    const int idx = b * 256 + t;          // 0..524287
    const int g = idx >> 15;
    const int rem = idx & 32767;
    const int i = rem >> 7;               // 0..255
    const int o = rem & 127;              // fastest -> coalesced source read
    const float v = W_mid[(g << 15) + i * 128 + o] * w_inp[g * 256 + i];
    Wtm[(g << 15) + o * 256 + i] = (ushort_t)f2bf_bits(v);
  } else if (b < 4096) {
    const int idx = (b - 2048) * 256 + t; // 0..524287
    const int k = idx >> 8;               // 0..2047
    const int o = idx & 255;              // fastest -> coalesced source read
    Wtr[o * 2048 + k] = (ushort_t)f2bf_bits(W_root[k * 256 + o]);
  } else {
    const int idx = (b - 4096) * 256 + t; // 0..2047
    const int g = idx >> 7;
    const int o = idx & 127;
    float s = b_mid[idx];
    for (int i = 0; i < 256; ++i)
      s += pbias[g * 4 + (i >> 6)] * W_mid[(g << 15) + i * 128 + o];
    bias_eff[idx] = s;
  }
}

// ---------- mid GEMM: mid[b, g*128+o] = tanh(x[b, g*256:+256] @ W'[g] + bias_eff[g]) ----------
// grid (128 m-tiles, 16 groups), block 256. Tile 128x128, BK=32, K=256.

__global__ __launch_bounds__(256) void midk(const float* __restrict__ x,
                                            const ushort_t* __restrict__ Wtm,
                                            const float* __restrict__ bias_eff,
                                            ushort_t* __restrict__ mid) {
  __shared__ __align__(16) unsigned char smem[34816];
  ushort_t* sA = (ushort_t*)smem;            // [128][40] bf16 (padded)
  ushort_t* sB = (ushort_t*)(smem + 10240);  // [128][32] bf16 (unpadded: global_load_lds)

  const int t = threadIdx.x;
  const int lane = t & 63;
  const int wv = __builtin_amdgcn_readfirstlane(t >> 6);
  const int g = blockIdx.y;
  const int m0 = blockIdx.x * 128;

  const int wm = (wv & 1) * 64;
  const int wn = (wv >> 1) * 64;

  // A staging: 2 threads per row, 16 floats each
  const int ar = t >> 1, ah = t & 1;
  const float* agp = x + (m0 + ar) * 4096 + g * 256 + ah * 16;
  ushort_t* asw = sA + ar * 40 + ah * 16;

  // B staging: per wave 2 calls of 16 rows each
  const ushort_t* bgp = Wtm + (g << 15) + (wv * 32 + (lane >> 2)) * 256 + (lane & 3) * 8;
  ushort_t* bl = sB + (wv * 32) * 32;

  floatx4 acc[4][4] = {};

  for (int kk = 0; kk < 8; ++kk) {
    __syncthreads();
    gl_lds16(bgp + kk * 32, bl);
    gl_lds16(bgp + 16 * 256 + kk * 32, bl + 16 * 32);

    const float4* ap4 = (const float4*)(agp + kk * 32);
    float4 f0 = ap4[0], f1 = ap4[1], f2 = ap4[2], f3 = ap4[3];
    uint32 u0 = f2bf_bits(f0.x) | (f2bf_bits(f0.y) << 16);
    uint32 u1 = f2bf_bits(f0.z) | (f2bf_bits(f0.w) << 16);
    uint32 u2 = f2bf_bits(f1.x) | (f2bf_bits(f1.y) << 16);
    uint32 u3 = f2bf_bits(f1.z) | (f2bf_bits(f1.w) << 16);
    uint32 u4 = f2bf_bits(f2.x) | (f2bf_bits(f2.y) << 16);
    uint32 u5 = f2bf_bits(f2.z) | (f2bf_bits(f2.w) << 16);
    uint32 u6 = f2bf_bits(f3.x) | (f2bf_bits(f3.y) << 16);
    uint32 u7 = f2bf_bits(f3.z) | (f2bf_bits(f3.w) << 16);
    ((uint4*)asw)[0] = make_uint4(u0, u1, u2, u3);
    ((uint4*)asw)[1] = make_uint4(u4, u5, u6, u7);
    __syncthreads();

    short8 af[4], bfrag[4];
#pragma unroll
    for (int mi = 0; mi < 4; ++mi)
      af[mi] = *(const short8*)(sA + (wm + mi * 16 + (lane & 15)) * 40 + (lane >> 4) * 8);
#pragma unroll
    for (int ni = 0; ni < 4; ++ni)
      bfrag[ni] = *(const short8*)(sB + (wn + ni * 16 + (lane & 15)) * 32 + (lane >> 4) * 8);
#pragma unroll
    for (int mi = 0; mi < 4; ++mi)
#pragma unroll
      for (int ni = 0; ni < 4; ++ni)
        acc[mi][ni] = __builtin_amdgcn_mfma_f32_16x16x32_bf16(af[mi], bfrag[ni], acc[mi][ni], 0, 0, 0);
  }

  // epilogue: bias + tanh + bf16, bounce through LDS for coalesced stores
  __syncthreads();
  ushort_t* sC = (ushort_t*)smem;  // [128][136] bf16
#pragma unroll
  for (int ni = 0; ni < 4; ++ni) {
    const int col = wn + ni * 16 + (lane & 15);
    const float bias = bias_eff[g * 128 + col];
#pragma unroll
    for (int mi = 0; mi < 4; ++mi) {
#pragma unroll
      for (int r = 0; r < 4; ++r) {
        const int row = wm + mi * 16 + (lane >> 4) * 4 + r;
        sC[row * 136 + col] = (ushort_t)f2bf_bits(tanh_fast(acc[mi][ni][r] + bias));
      }
    }
  }
  __syncthreads();
  const int rr = t >> 1, hh = t & 1;
  const uint4* src = (const uint4*)(sC + rr * 136 + hh * 64);
  uint4* dst = (uint4*)(mid + (m0 + rr) * 2048 + g * 128 + hh * 64);
#pragma unroll
  for (int i = 0; i < 8; ++i) dst[i] = src[i];
}

// ---------- root GEMM: out = mid @ W_root + b_root ----------
// grid (128 m-tiles, 2 n-tiles, 2 k-splits), block 256. Tile 128x128, BK=32.
// Split-K partial sums via fp32 atomicAdd (out pre-zeroed by memsetAsync).

__global__ __launch_bounds__(256) void rootk(const ushort_t* __restrict__ mid,
                                             const ushort_t* __restrict__ Wtr,
                                             const float* __restrict__ b_root,
                                             float* __restrict__ out) {
  __shared__ __align__(16) ushort_t sA[128 * 32];
  __shared__ __align__(16) ushort_t sB[128 * 32];

  const int t = threadIdx.x;
  const int lane = t & 63;
  const int wv = __builtin_amdgcn_readfirstlane(t >> 6);
  const int m0 = blockIdx.x * 128;
  const int n0 = blockIdx.y * 128;
  const int kz = blockIdx.z;

  const int wm = (wv & 1) * 64;
  const int wn = (wv >> 1) * 64;

  const ushort_t* ag = mid + (m0 + wv * 32 + (lane >> 2)) * 2048 + kz * 1024 + (lane & 3) * 8;
  const ushort_t* bg = Wtr + (n0 + wv * 32 + (lane >> 2)) * 2048 + kz * 1024 + (lane & 3) * 8;
  ushort_t* al = sA + (wv * 32) * 32;
  ushort_t* bl = sB + (wv * 32) * 32;

  floatx4 acc[4][4] = {};

  for (int kk = 0; kk < 32; ++kk) {
    __syncthreads();
    gl_lds16(ag + kk * 32, al);
    gl_lds16(ag + 16 * 2048 + kk * 32, al + 16 * 32);
    gl_lds16(bg + kk * 32, bl);
    gl_lds16(bg + 16 * 2048 + kk * 32, bl + 16 * 32);
    __syncthreads();

    short8 af[4], bfrag[4];
#pragma unroll
    for (int mi = 0; mi < 4; ++mi)
      af[mi] = *(const short8*)(sA + (wm + mi * 16 + (lane & 15)) * 32 + (lane >> 4) * 8);
#pragma unroll
    for (int ni = 0; ni < 4; ++ni)
      bfrag[ni] = *(const short8*)(sB + (wn + ni * 16 + (lane & 15)) * 32 + (lane >> 4) * 8);
#pragma unroll
    for (int mi = 0; mi < 4; ++mi)
#pragma unroll
      for (int ni = 0; ni < 4; ++ni)
        acc[mi][ni] = __builtin_amdgcn_mfma_f32_16x16x32_bf16(af[mi], bfrag[ni], acc[mi][ni], 0, 0, 0);
  }

#pragma unroll
  for (int ni = 0; ni < 4; ++ni) {
    const int col = n0 + wn + ni * 16 + (lane & 15);
    const float br = (kz == 0) ? b_root[col] : 0.0f;
#pragma unroll
    for (int mi = 0; mi < 4; ++mi)
#pragma unroll
      for (int r = 0; r < 4; ++r) {
        const int row = m0 + wm + mi * 16 + (lane >> 4) * 4 + r;
        atomicAdd(out + row * 256 + col, acc[mi][ni][r] + br);
      }
  }
}

// ---------- launch ----------

extern "C" void kernel_launch(void* const* d_in, const int* in_sizes, int n_in,
                              void* d_out, int out_size, void* d_ws, size_t ws_size,
                              hipStream_t stream) {
  const float* x      = (const float*)d_in[0];
  const float* w_inp  = (const float*)d_in[1];
  const float* pbias  = (const float*)d_in[2];
  const float* W_mid  = (const float*)d_in[3];
  const float* b_mid  = (const float*)d_in[4];
  const float* W_root = (const float*)d_in[5];
  const float* b_root = (const float*)d_in[6];
  float* out = (float*)d_out;

  char* ws = (char*)d_ws;
  ushort_t* Wtm      = (ushort_t*)(ws);
  ushort_t* Wtr      = (ushort_t*)(ws + (1 << 20));
  float*    bias_eff = (float*)   (ws + (2 << 20));
  ushort_t* midbuf   = (ushort_t*)(ws + (4 << 20));

  hipMemsetAsync(d_out, 0, (size_t)out_size * sizeof(float), stream);
  prep<<<dim3(4104), dim3(256), 0, stream>>>(w_inp, pbias, W_mid, b_mid, W_root, Wtm, Wtr, bias_eff);
  midk<<<dim3(128, 16), dim3(256), 0, stream>>>(x, Wtm, bias_eff, midbuf);
  rootk<<<dim3(128, 2, 2), dim3(256), 0, stream>>>(midbuf, Wtr, b_root, out);
}

// Round 2
// 463.168 us; speedup vs baseline: 1.0265x; 1.0265x over previous
//
#include <hip/hip_runtime.h>

typedef __attribute__((ext_vector_type(8))) short short8;
typedef __attribute__((ext_vector_type(4))) float floatx4;
typedef unsigned short ushort_t;
typedef unsigned int uint32;

// ---------- helpers ----------

__device__ __forceinline__ uint32 f2bf_bits(float f) {
  uint32 u = __builtin_bit_cast(uint32, f);
  u += 0x7fffu + ((u >> 16) & 1u);   // round-to-nearest-even
  return u >> 16;
}

__device__ __forceinline__ float tanh_fast(float x) {
  float e = __expf(2.0f * x);
  return 1.0f - 2.0f * __builtin_amdgcn_rcpf(e + 1.0f);
}

__device__ __forceinline__ void gl_lds16(const void* g, void* l) {
  __builtin_amdgcn_global_load_lds((const __attribute__((address_space(1))) void*)g,
                                   (__attribute__((address_space(3))) void*)l,
                                   16, 0, 0);
}

// ---------- prep: fold weights, cast to bf16, pre-transpose to [n][k] ----------
// ws layout:
//   Wtm      [16][128 o][256 i] bf16   @ 0      (W_mid * w_inp, transposed)
//   Wtr      [256 o][2048 k]    bf16   @ 1 MB   (W_root transposed)
//   bias_eff [16][128]          f32    @ 2 MB   (b_mid + sum_i pbias*W_mid)
//   midbuf   [16384][2048]      bf16   @ 4 MB   (tanh outputs)
//   partial  [2][16384][256]    f32    @ 72 MB  (root split-K partials)

__global__ __launch_bounds__(256) void prep(const float* __restrict__ w_inp,
                                            const float* __restrict__ pbias,
                                            const float* __restrict__ W_mid,
                                            const float* __restrict__ b_mid,
                                            const float* __restrict__ W_root,
                                            ushort_t* __restrict__ Wtm,
                                            ushort_t* __restrict__ Wtr,
                                            float* __restrict__ bias_eff) {
  const int b = blockIdx.x, t = threadIdx.x;
  if (b < 2048) {
    // W'_mid: read coalesced over o, write transposed
    const int idx = b * 256 + t;          // 0..524287
    const int g = idx >> 15;
    const int rem = idx & 32767;
    const int i = rem >> 7;               // 0..255
    const int o = rem & 127;              // fastest -> coalesced source read
    const float v = W_mid[(g << 15) + i * 128 + o] * w_inp[g * 256 + i];
    Wtm[(g << 15) + o * 256 + i] = (ushort_t)f2bf_bits(v);
  } else if (b < 4096) {
    const int idx = (b - 2048) * 256 + t; // 0..524287
    const int k = idx >> 8;               // 0..2047
    const int o = idx & 255;              // fastest -> coalesced source read
    Wtr[o * 2048 + k] = (ushort_t)f2bf_bits(W_root[k * 256 + o]);
  } else {
    // bias_eff: one block per group, coalesced over o, unrolled over i for ILP
    const int g = b - 4096;               // 0..15
    const int o = t;
    if (o < 128) {
      float s = b_mid[g * 128 + o];
      const float* wp = W_mid + (g << 15) + o;
      float pb[4];
#pragma unroll
      for (int q = 0; q < 4; ++q) pb[q] = pbias[g * 4 + q];
#pragma unroll 8
      for (int i = 0; i < 256; ++i) s += pb[i >> 6] * wp[i * 128];
      bias_eff[g * 128 + o] = s;
    }
  }
}

// ---------- mid GEMM: mid[b, g*128+o] = tanh(x[b, g*256:+256] @ W'[g] + bias_eff[g]) ----------
// grid (128 m-tiles, 16 groups), block 256. Tile 128x128, BK=32, K=256.

__global__ __launch_bounds__(256) void midk(const float* __restrict__ x,
                                            const ushort_t* __restrict__ Wtm,
                                            const float* __restrict__ bias_eff,
                                            ushort_t* __restrict__ mid) {
  __shared__ __align__(16) unsigned char smem[34816];
  ushort_t* sA = (ushort_t*)smem;            // [128][40] bf16 (padded)
  ushort_t* sB = (ushort_t*)(smem + 10240);  // [128][32] bf16 (unpadded: global_load_lds)

  const int t = threadIdx.x;
  const int lane = t & 63;
  const int wv = __builtin_amdgcn_readfirstlane(t >> 6);
  const int g = blockIdx.y;
  const int m0 = blockIdx.x * 128;

  const int wm = (wv & 1) * 64;
  const int wn = (wv >> 1) * 64;

  // A staging: 2 threads per row, 16 floats each
  const int ar = t >> 1, ah = t & 1;
  const float* agp = x + (m0 + ar) * 4096 + g * 256 + ah * 16;
  ushort_t* asw = sA + ar * 40 + ah * 16;

  // B staging: per wave 2 calls of 16 rows each
  const ushort_t* bgp = Wtm + (g << 15) + (wv * 32 + (lane >> 2)) * 256 + (lane & 3) * 8;
  ushort_t* bl = sB + (wv * 32) * 32;

  floatx4 acc[4][4] = {};

  for (int kk = 0; kk < 8; ++kk) {
    __syncthreads();
    gl_lds16(bgp + kk * 32, bl);
    gl_lds16(bgp + 16 * 256 + kk * 32, bl + 16 * 32);

    const float4* ap4 = (const float4*)(agp + kk * 32);
    float4 f0 = ap4[0], f1 = ap4[1], f2 = ap4[2], f3 = ap4[3];
    uint32 u0 = f2bf_bits(f0.x) | (f2bf_bits(f0.y) << 16);
    uint32 u1 = f2bf_bits(f0.z) | (f2bf_bits(f0.w) << 16);
    uint32 u2 = f2bf_bits(f1.x) | (f2bf_bits(f1.y) << 16);
    uint32 u3 = f2bf_bits(f1.z) | (f2bf_bits(f1.w) << 16);
    uint32 u4 = f2bf_bits(f2.x) | (f2bf_bits(f2.y) << 16);
    uint32 u5 = f2bf_bits(f2.z) | (f2bf_bits(f2.w) << 16);
    uint32 u6 = f2bf_bits(f3.x) | (f2bf_bits(f3.y) << 16);
    uint32 u7 = f2bf_bits(f3.z) | (f2bf_bits(f3.w) << 16);
    ((uint4*)asw)[0] = make_uint4(u0, u1, u2, u3);
    ((uint4*)asw)[1] = make_uint4(u4, u5, u6, u7);
    __syncthreads();

    short8 af[4], bfrag[4];
#pragma unroll
    for (int mi = 0; mi < 4; ++mi)
      af[mi] = *(const short8*)(sA + (wm + mi * 16 + (lane & 15)) * 40 + (lane >> 4) * 8);
#pragma unroll
    for (int ni = 0; ni < 4; ++ni)
      bfrag[ni] = *(const short8*)(sB + (wn + ni * 16 + (lane & 15)) * 32 + (lane >> 4) * 8);
#pragma unroll
    for (int mi = 0; mi < 4; ++mi)
#pragma unroll
      for (int ni = 0; ni < 4; ++ni)
        acc[mi][ni] = __builtin_amdgcn_mfma_f32_16x16x32_bf16(af[mi], bfrag[ni], acc[mi][ni], 0, 0, 0);
  }

  // epilogue: bias + tanh + bf16, bounce through LDS for coalesced stores
  __syncthreads();
  ushort_t* sC = (ushort_t*)smem;  // [128][136] bf16
#pragma unroll
  for (int ni = 0; ni < 4; ++ni) {
    const int col = wn + ni * 16 + (lane & 15);
    const float bias = bias_eff[g * 128 + col];
#pragma unroll
    for (int mi = 0; mi < 4; ++mi) {
#pragma unroll
      for (int r = 0; r < 4; ++r) {
        const int row = wm + mi * 16 + (lane >> 4) * 4 + r;
        sC[row * 136 + col] = (ushort_t)f2bf_bits(tanh_fast(acc[mi][ni][r] + bias));
      }
    }
  }
  __syncthreads();
  const int rr = t >> 1, hh = t & 1;
  const uint4* src = (const uint4*)(sC + rr * 136 + hh * 64);
  uint4* dst = (uint4*)(mid + (m0 + rr) * 2048 + g * 128 + hh * 64);
#pragma unroll
  for (int i = 0; i < 8; ++i) dst[i] = src[i];
}

// ---------- root GEMM: partial[kz] = mid[:, kz*1024:+1024] @ W_root[kz slice] ----------
// grid (128 m-tiles, 2 n-tiles, 2 k-splits), block 256. Tile 128x128, BK=32.
// Deterministic split-K: plain f32 stores to ws partials, reduced by reducek.

__global__ __launch_bounds__(256) void rootk(const ushort_t* __restrict__ mid,
                                             const ushort_t* __restrict__ Wtr,
                                             float* __restrict__ partial) {
  __shared__ __align__(16) ushort_t sA[128 * 32];
  __shared__ __align__(16) ushort_t sB[128 * 32];

  const int t = threadIdx.x;
  const int lane = t & 63;
  const int wv = __builtin_amdgcn_readfirstlane(t >> 6);
  const int m0 = blockIdx.x * 128;
  const int n0 = blockIdx.y * 128;
  const int kz = blockIdx.z;

  const int wm = (wv & 1) * 64;
  const int wn = (wv >> 1) * 64;

  const ushort_t* ag = mid + (m0 + wv * 32 + (lane >> 2)) * 2048 + kz * 1024 + (lane & 3) * 8;
  const ushort_t* bg = Wtr + (n0 + wv * 32 + (lane >> 2)) * 2048 + kz * 1024 + (lane & 3) * 8;
  ushort_t* al = sA + (wv * 32) * 32;
  ushort_t* bl = sB + (wv * 32) * 32;

  floatx4 acc[4][4] = {};

  for (int kk = 0; kk < 32; ++kk) {
    __syncthreads();
    gl_lds16(ag + kk * 32, al);
    gl_lds16(ag + 16 * 2048 + kk * 32, al + 16 * 32);
    gl_lds16(bg + kk * 32, bl);
    gl_lds16(bg + 16 * 2048 + kk * 32, bl + 16 * 32);
    __syncthreads();

    short8 af[4], bfrag[4];
#pragma unroll
    for (int mi = 0; mi < 4; ++mi)
      af[mi] = *(const short8*)(sA + (wm + mi * 16 + (lane & 15)) * 32 + (lane >> 4) * 8);
#pragma unroll
    for (int ni = 0; ni < 4; ++ni)
      bfrag[ni] = *(const short8*)(sB + (wn + ni * 16 + (lane & 15)) * 32 + (lane >> 4) * 8);
#pragma unroll
    for (int mi = 0; mi < 4; ++mi)
#pragma unroll
      for (int ni = 0; ni < 4; ++ni)
        acc[mi][ni] = __builtin_amdgcn_mfma_f32_16x16x32_bf16(af[mi], bfrag[ni], acc[mi][ni], 0, 0, 0);
  }

  float* pout = partial + (size_t)kz * (16384 * 256);
#pragma unroll
  for (int ni = 0; ni < 4; ++ni) {
    const int col = n0 + wn + ni * 16 + (lane & 15);
#pragma unroll
    for (int mi = 0; mi < 4; ++mi)
#pragma unroll
      for (int r = 0; r < 4; ++r) {
        const int row = m0 + wm + mi * 16 + (lane >> 4) * 4 + r;
        pout[row * 256 + col] = acc[mi][ni][r];
      }
  }
}

// ---------- reduce: out = p0 + p1 + b_root ----------

__global__ __launch_bounds__(256) void reducek(const float* __restrict__ partial,
                                               const float* __restrict__ b_root,
                                               float* __restrict__ out) {
  const int i4 = (blockIdx.x * 256 + threadIdx.x) * 4;
  float4 a = *(const float4*)(partial + i4);
  float4 b = *(const float4*)(partial + (16384 * 256) + i4);
  float4 c = *(const float4*)(b_root + (i4 & 255));
  float4 r = make_float4(a.x + b.x + c.x, a.y + b.y + c.y,
                         a.z + b.z + c.z, a.w + b.w + c.w);
  *(float4*)(out + i4) = r;
}

// ---------- launch ----------

extern "C" void kernel_launch(void* const* d_in, const int* in_sizes, int n_in,
                              void* d_out, int out_size, void* d_ws, size_t ws_size,
                              hipStream_t stream) {
  const float* x      = (const float*)d_in[0];
  const float* w_inp  = (const float*)d_in[1];
  const float* pbias  = (const float*)d_in[2];
  const float* W_mid  = (const float*)d_in[3];
  const float* b_mid  = (const float*)d_in[4];
  const float* W_root = (const float*)d_in[5];
  const float* b_root = (const float*)d_in[6];
  float* out = (float*)d_out;

  char* ws = (char*)d_ws;
  ushort_t* Wtm      = (ushort_t*)(ws);
  ushort_t* Wtr      = (ushort_t*)(ws + (1 << 20));
  float*    bias_eff = (float*)   (ws + (2 << 20));
  ushort_t* midbuf   = (ushort_t*)(ws + (4 << 20));
  float*    partials = (float*)   (ws + (72u << 20));

  prep<<<dim3(4112), dim3(256), 0, stream>>>(w_inp, pbias, W_mid, b_mid, W_root, Wtm, Wtr, bias_eff);
  midk<<<dim3(128, 16), dim3(256), 0, stream>>>(x, Wtm, bias_eff, midbuf);
  rootk<<<dim3(128, 2, 2), dim3(256), 0, stream>>>(midbuf, Wtr, partials);
  reducek<<<dim3(4096), dim3(256), 0, stream>>>(partials, b_root, out);
}

// Round 3
// 452.162 us; speedup vs baseline: 1.0515x; 1.0243x over previous
//
#include <hip/hip_runtime.h>

typedef __attribute__((ext_vector_type(8))) short short8;
typedef __attribute__((ext_vector_type(4))) float floatx4;
typedef unsigned short ushort_t;
typedef unsigned int uint32;

// ---------- helpers ----------

__device__ __forceinline__ uint32 f2bf_bits(float f) {
  uint32 u = __builtin_bit_cast(uint32, f);
  u += 0x7fffu + ((u >> 16) & 1u);   // round-to-nearest-even
  return u >> 16;
}

__device__ __forceinline__ float tanh_fast(float x) {
  float e = __expf(2.0f * x);
  return 1.0f - 2.0f * __builtin_amdgcn_rcpf(e + 1.0f);
}

#define MFMA16(a, b, c) __builtin_amdgcn_mfma_f32_16x16x32_bf16((a), (b), (c), 0, 0, 0)

// ---------- prep: fold weights, cast to bf16, pre-transpose to [n][k] ----------
// ws layout:
//   Wtm      [16][128 o][256 i] bf16   @ 0      (W_mid * w_inp, transposed)
//   Wtr      [256 o][2048 k]    bf16   @ 1 MB   (W_root transposed)
//   bias_eff [16][128]          f32    @ 2 MB   (b_mid + sum_i pbias*W_mid)

__global__ __launch_bounds__(256) void prep(const float* __restrict__ w_inp,
                                            const float* __restrict__ pbias,
                                            const float* __restrict__ W_mid,
                                            const float* __restrict__ b_mid,
                                            const float* __restrict__ W_root,
                                            ushort_t* __restrict__ Wtm,
                                            ushort_t* __restrict__ Wtr,
                                            float* __restrict__ bias_eff) {
  const int b = blockIdx.x, t = threadIdx.x;
  if (b < 2048) {
    const int idx = b * 256 + t;          // 0..524287
    const int g = idx >> 15;
    const int rem = idx & 32767;
    const int i = rem >> 7;               // 0..255
    const int o = rem & 127;              // fastest -> coalesced source read
    const float v = W_mid[(g << 15) + i * 128 + o] * w_inp[g * 256 + i];
    Wtm[(g << 15) + o * 256 + i] = (ushort_t)f2bf_bits(v);
  } else if (b < 4096) {
    const int idx = (b - 2048) * 256 + t; // 0..524287
    const int k = idx >> 8;               // 0..2047
    const int o = idx & 255;              // fastest -> coalesced source read
    Wtr[o * 2048 + k] = (ushort_t)f2bf_bits(W_root[k * 256 + o]);
  } else {
    const int g = b - 4096;               // 0..15
    const int o = t;
    if (o < 128) {
      float s = b_mid[g * 128 + o];
      const float* wp = W_mid + (g << 15) + o;
      float pb[4];
#pragma unroll
      for (int q = 0; q < 4; ++q) pb[q] = pbias[g * 4 + q];
#pragma unroll 8
      for (int i = 0; i < 256; ++i) s += pb[i >> 6] * wp[i * 128];
      bias_eff[g * 128 + o] = s;
    }
  }
}

// ---------- fused mid+root ----------
// Block: 256 threads (4 waves), 32 batch rows. Grid 512.
// Per group g: stage x_g (fp32->bf16) into sX, mid GEMM (32x128, K=256) with
// Wtm B-frags streamed from L2, tanh -> sMid, root partial (32x256, K=128)
// accumulated in registers with Wtr B-frags streamed from L2.
// LDS: sX 32x264 bf16 (16.9 KB) + sMid 32x136 bf16 (8.7 KB) = 25.6 KB.

__global__ __launch_bounds__(256) void fused(const float* __restrict__ x,
                                             const ushort_t* __restrict__ Wtm,
                                             const ushort_t* __restrict__ Wtr,
                                             const float* __restrict__ bias_eff,
                                             const float* __restrict__ b_root,
                                             float* __restrict__ out) {
  __shared__ __align__(16) ushort_t sX[32 * 264];   // stride 264: 16B-aligned rows, 2-way banks max
  __shared__ __align__(16) ushort_t sMid[32 * 136]; // stride 136: same properties

  const int t = threadIdx.x;
  const int lane = t & 63;
  const int wv = __builtin_amdgcn_readfirstlane(t >> 6);
  const int m0 = blockIdx.x * 32;
  const int l15 = lane & 15;
  const int kh = lane >> 4;          // 0..3

  // x staging: thread t handles row xr = t>>3, float4-slot xq = t&7 (+8 per pass)
  const int xr = t >> 3, xq = t & 7;
  const float* xbase = x + (size_t)(m0 + xr) * 4096 + xq * 4;
  uint32* sxw = (uint32*)(sX + xr * 264 + xq * 4);

  // A-frag LDS read pointers (a-frag: m = mi*16 + l15, k-chunk = kh*8)
  const ushort_t* sxa0 = sX + l15 * 264 + kh * 8;
  const ushort_t* sxa1 = sX + (16 + l15) * 264 + kh * 8;
  const ushort_t* sma0 = sMid + l15 * 136 + kh * 8;
  const ushort_t* sma1 = sMid + (16 + l15) * 136 + kh * 8;

  // B-frag global bases (L2-resident weights)
  const ushort_t* wtm_b0 = Wtm + (wv * 32 + l15) * 256 + kh * 8;
  const ushort_t* wtm_b1 = Wtm + (wv * 32 + 16 + l15) * 256 + kh * 8;
  const ushort_t* wtr_b  = Wtr + (wv * 64 + l15) * 2048 + kh * 8;

  float4 rx[8];
  floatx4 racc[2][4] = {};

  // preload x for group 0
#pragma unroll
  for (int p = 0; p < 8; ++p) rx[p] = *(const float4*)(xbase + p * 32);

  for (int g = 0; g < 16; ++g) {
    __syncthreads();  // (a) prior group's sX/sMid reads complete

    // convert rx (group g) -> sX, round-half-up + byte-perm pack
#pragma unroll
    for (int p = 0; p < 8; ++p) {
      uint32 bx = __builtin_bit_cast(uint32, rx[p].x) + 0x8000u;
      uint32 by = __builtin_bit_cast(uint32, rx[p].y) + 0x8000u;
      uint32 bz = __builtin_bit_cast(uint32, rx[p].z) + 0x8000u;
      uint32 bw = __builtin_bit_cast(uint32, rx[p].w) + 0x8000u;
      uint32 lo = __builtin_amdgcn_perm(by, bx, 0x07060302u);
      uint32 hi = __builtin_amdgcn_perm(bw, bz, 0x07060302u);
      *(uint2*)(sxw + p * 16) = make_uint2(lo, hi);
    }

    // mid B preload (kk=0,1) BEFORE x prefetch so first MFMAs don't wait on HBM
    const ushort_t* wb0 = wtm_b0 + (g << 15);
    const ushort_t* wb1 = wtm_b1 + (g << 15);
    short8 mb[2][2];
    mb[0][0] = *(const short8*)(wb0);
    mb[0][1] = *(const short8*)(wb1);
    mb[1][0] = *(const short8*)(wb0 + 32);
    mb[1][1] = *(const short8*)(wb1 + 32);

    // prefetch next group's x into registers (overlaps with both MFMA phases)
    {
      const float* xn = xbase + (g < 15 ? g + 1 : 15) * 256;
#pragma unroll
      for (int p = 0; p < 8; ++p) rx[p] = *(const float4*)(xn + p * 32);
    }

    const float bias0 = bias_eff[g * 128 + wv * 32 + l15];
    const float bias1 = bias_eff[g * 128 + wv * 32 + 16 + l15];

    __syncthreads();  // (b) sX ready

    // ---- mid GEMM: 32x128 (wave: 32m x 32n), K=256 ----
    floatx4 macc[2][2] = {};
#pragma unroll
    for (int kk = 0; kk < 8; ++kk) {
      short8 a0 = *(const short8*)(sxa0 + kk * 32);
      short8 a1 = *(const short8*)(sxa1 + kk * 32);
      short8 b0 = mb[kk & 1][0], b1 = mb[kk & 1][1];
      const int kn = (kk + 2 <= 7) ? kk + 2 : 7;
      mb[kk & 1][0] = *(const short8*)(wb0 + kn * 32);
      mb[kk & 1][1] = *(const short8*)(wb1 + kn * 32);
      macc[0][0] = MFMA16(a0, b0, macc[0][0]);
      macc[0][1] = MFMA16(a0, b1, macc[0][1]);
      macc[1][0] = MFMA16(a1, b0, macc[1][0]);
      macc[1][1] = MFMA16(a1, b1, macc[1][1]);
    }

    // ---- epilogue: bias + tanh -> sMid (bf16, root-A layout) ----
#pragma unroll
    for (int ni = 0; ni < 2; ++ni) {
      const float bias = ni ? bias1 : bias0;
      const int col = wv * 32 + ni * 16 + l15;
#pragma unroll
      for (int mi = 0; mi < 2; ++mi)
#pragma unroll
        for (int r = 0; r < 4; ++r) {
          const int row = mi * 16 + kh * 4 + r;
          sMid[row * 136 + col] = (ushort_t)f2bf_bits(tanh_fast(macc[mi][ni][r] + bias));
        }
    }

    // root B preload (kk2=0,1) before the barrier
    const ushort_t* wb = wtr_b + g * 128;
    short8 rb[2][4];
#pragma unroll
    for (int ni = 0; ni < 4; ++ni) rb[0][ni] = *(const short8*)(wb + ni * 16 * 2048);
#pragma unroll
    for (int ni = 0; ni < 4; ++ni) rb[1][ni] = *(const short8*)(wb + ni * 16 * 2048 + 32);

    __syncthreads();  // (c) sMid ready

    // ---- root partial: 32x256 (wave: 32m x 64n), K=128, accumulate in racc ----
#pragma unroll
    for (int kk2 = 0; kk2 < 4; ++kk2) {
      short8 a0 = *(const short8*)(sma0 + kk2 * 32);
      short8 a1 = *(const short8*)(sma1 + kk2 * 32);
      short8 b0 = rb[kk2 & 1][0], b1 = rb[kk2 & 1][1];
      short8 b2 = rb[kk2 & 1][2], b3 = rb[kk2 & 1][3];
      const int kn = (kk2 + 2 <= 3) ? kk2 + 2 : 3;
#pragma unroll
      for (int ni = 0; ni < 4; ++ni)
        rb[kk2 & 1][ni] = *(const short8*)(wb + ni * 16 * 2048 + kn * 32);
      racc[0][0] = MFMA16(a0, b0, racc[0][0]);
      racc[0][1] = MFMA16(a0, b1, racc[0][1]);
      racc[0][2] = MFMA16(a0, b2, racc[0][2]);
      racc[0][3] = MFMA16(a0, b3, racc[0][3]);
      racc[1][0] = MFMA16(a1, b0, racc[1][0]);
      racc[1][1] = MFMA16(a1, b1, racc[1][1]);
      racc[1][2] = MFMA16(a1, b2, racc[1][2]);
      racc[1][3] = MFMA16(a1, b3, racc[1][3]);
    }
  }

  // ---- final store: out = racc + b_root (fp32, coalesced 64B per quarter-wave) ----
#pragma unroll
  for (int ni = 0; ni < 4; ++ni) {
    const int col = wv * 64 + ni * 16 + l15;
    const float br = b_root[col];
#pragma unroll
    for (int mi = 0; mi < 2; ++mi)
#pragma unroll
      for (int r = 0; r < 4; ++r) {
        const int row = m0 + mi * 16 + kh * 4 + r;
        out[row * 256 + col] = racc[mi][ni][r] + br;
      }
  }
}

// ---------- launch ----------

extern "C" void kernel_launch(void* const* d_in, const int* in_sizes, int n_in,
                              void* d_out, int out_size, void* d_ws, size_t ws_size,
                              hipStream_t stream) {
  const float* x      = (const float*)d_in[0];
  const float* w_inp  = (const float*)d_in[1];
  const float* pbias  = (const float*)d_in[2];
  const float* W_mid  = (const float*)d_in[3];
  const float* b_mid  = (const float*)d_in[4];
  const float* W_root = (const float*)d_in[5];
  const float* b_root = (const float*)d_in[6];
  float* out = (float*)d_out;

  char* ws = (char*)d_ws;
  ushort_t* Wtm      = (ushort_t*)(ws);
  ushort_t* Wtr      = (ushort_t*)(ws + (1 << 20));
  float*    bias_eff = (float*)   (ws + (2 << 20));

  prep<<<dim3(4112), dim3(256), 0, stream>>>(w_inp, pbias, W_mid, b_mid, W_root, Wtm, Wtr, bias_eff);
  fused<<<dim3(512), dim3(256), 0, stream>>>(x, Wtm, Wtr, bias_eff, b_root, out);
}